// Round 15
// baseline (344.830 us; speedup 1.0000x reference)
//
#include <hip/hip_runtime.h>
#include <hip/hip_bf16.h>

// MultiHeadAttention fused pipeline for MI355X (gfx950).
// b=2, t=s=2048, E=1024, H=16, D=64. Outputs: out fp32 [2,2048,1024], attn fp32 [32,2048,2048].

typedef __attribute__((ext_vector_type(8))) __bf16 bf16x8;
typedef __attribute__((ext_vector_type(4))) float f32x4;
typedef __attribute__((ext_vector_type(8))) unsigned short us8;

#define MFMA16(A, B, C) __builtin_amdgcn_mfma_f32_16x16x32_bf16(A, B, C, 0, 0, 0)

__device__ __forceinline__ unsigned short f2bf(float f) {
  __bf16 h = (__bf16)f;
  return __builtin_bit_cast(unsigned short, h);
}

// ---------------- fused fp32 -> bf16 convert for all 7 tensors ----------------
__global__ __launch_bounds__(256) void cvt_all_kernel(
    const float* __restrict__ q, const float* __restrict__ k, const float* __restrict__ v,
    const float* __restrict__ Wq, const float* __restrict__ Wk,
    const float* __restrict__ Wv, const float* __restrict__ Wo,
    unsigned short* __restrict__ qb, unsigned short* __restrict__ kb,
    unsigned short* __restrict__ vb, unsigned short* __restrict__ wqb,
    unsigned short* __restrict__ wkb, unsigned short* __restrict__ wvb,
    unsigned short* __restrict__ wob) {
  const int bid = blockIdx.x;
  const float* src;
  unsigned short* dst;
  int i;
  if (bid < 4096)       { src = q; dst = qb; i = bid * 256 + threadIdx.x; }
  else if (bid < 8192)  { src = k; dst = kb; i = (bid - 4096) * 256 + threadIdx.x; }
  else if (bid < 12288) { src = v; dst = vb; i = (bid - 8192) * 256 + threadIdx.x; }
  else {
    int wsel = (bid - 12288) >> 10;
    i = ((bid - 12288) & 1023) * 256 + threadIdx.x;
    src = wsel == 0 ? Wq : wsel == 1 ? Wk : wsel == 2 ? Wv : Wo;
    dst = wsel == 0 ? wqb : wsel == 1 ? wkb : wsel == 2 ? wvb : wob;
  }
  float4 vv = ((const float4*)src)[i];
  ushort4 o;
  o.x = f2bf(vv.x); o.y = f2bf(vv.y); o.z = f2bf(vv.z); o.w = f2bf(vv.w);
  ((ushort4*)dst)[i] = o;
}

// ------- GEMM body (r10-proven): C[128x128 tile] = A @ W^T + bias, *scale -------
// MODE: 0 = bf16 [M][1024], 1 = fp32 [M][1024], 2 = bf16 transposed-per-head Vt layout
template <int MODE>
__device__ __forceinline__ void gemm_body(
    const unsigned short* __restrict__ A, const unsigned short* __restrict__ Bw,
    const float* __restrict__ bias, void* __restrict__ Cout, float scale,
    int m0, int n0) {
  __shared__ short As[128 * 72];
  __shared__ short Bs[128 * 72];
  const int tid = threadIdx.x;
  const int l = tid & 63, w = tid >> 6;
  const int lq = l >> 4, lr = l & 15;
  const int wr = w >> 1, wc = w & 1;

  uint4 va[4], vb[4];
#pragma unroll
  for (int i = 0; i < 4; ++i) {
    int c = i * 256 + tid, r = c >> 3, c8 = c & 7;
    va[i] = *(const uint4*)(A + (size_t)(m0 + r) * 1024 + c8 * 8);
    vb[i] = *(const uint4*)(Bw + (size_t)(n0 + r) * 1024 + c8 * 8);
  }
  const f32x4 fz = {0.f, 0.f, 0.f, 0.f};
  f32x4 acc[4][4];
#pragma unroll
  for (int m = 0; m < 4; ++m)
#pragma unroll
    for (int n = 0; n < 4; ++n) acc[m][n] = fz;

  for (int ks = 0; ks < 16; ++ks) {
    __syncthreads();
#pragma unroll
    for (int i = 0; i < 4; ++i) {
      int c = i * 256 + tid, r = c >> 3, c8 = c & 7;
      *(uint4*)((char*)As + r * 144 + c8 * 16) = va[i];
      *(uint4*)((char*)Bs + r * 144 + c8 * 16) = vb[i];
    }
    __syncthreads();
    if (ks < 15) {
      int k0 = (ks + 1) * 64;
#pragma unroll
      for (int i = 0; i < 4; ++i) {
        int c = i * 256 + tid, r = c >> 3, c8 = c & 7;
        va[i] = *(const uint4*)(A + (size_t)(m0 + r) * 1024 + k0 + c8 * 8);
        vb[i] = *(const uint4*)(Bw + (size_t)(n0 + r) * 1024 + k0 + c8 * 8);
      }
    }
#pragma unroll
    for (int kk = 0; kk < 2; ++kk) {
      bf16x8 af[4], bfr[4];
#pragma unroll
      for (int m = 0; m < 4; ++m)
        af[m] = *(const bf16x8*)((const char*)As + (wr * 64 + m * 16 + lr) * 144 + kk * 64 + lq * 16);
#pragma unroll
      for (int n = 0; n < 4; ++n)
        bfr[n] = *(const bf16x8*)((const char*)Bs + (wc * 64 + n * 16 + lr) * 144 + kk * 64 + lq * 16);
#pragma unroll
      for (int m = 0; m < 4; ++m)
#pragma unroll
        for (int n = 0; n < 4; ++n) acc[m][n] = MFMA16(af[m], bfr[n], acc[m][n]);
    }
  }
  // epilogue: C row = (lane>>4)*4+reg, col = lane&15
#pragma unroll
  for (int n = 0; n < 4; ++n) {
    const int col = n0 + wc * 64 + n * 16 + lr;
    const float bv_ = bias[col];
#pragma unroll
    for (int m = 0; m < 4; ++m) {
      const int rowb = m0 + wr * 64 + m * 16 + lq * 4;
      if (MODE == 2) {
        // direct transposed-per-head write: Vt[((b*16+h)*64+d)][key], 4 consecutive keys
        const int b_ = rowb >> 11, s = rowb & 2047;
        const size_t vtrow = (size_t)(b_ * 16 + (col >> 6)) * 64 + (col & 63);
        ushort4 o;
        o.x = f2bf(acc[m][n][0] + bv_);
        o.y = f2bf(acc[m][n][1] + bv_);
        o.z = f2bf(acc[m][n][2] + bv_);
        o.w = f2bf(acc[m][n][3] + bv_);
        *(ushort4*)((unsigned short*)Cout + vtrow * 2048 + s) = o;
      } else {
#pragma unroll
        for (int r = 0; r < 4; ++r) {
          float vv = (acc[m][n][r] + bv_) * scale;
          if (MODE == 1)
            ((float*)Cout)[(size_t)(rowb + r) * 1024 + col] = vv;
          else
            ((unsigned short*)Cout)[(size_t)(rowb + r) * 1024 + col] = f2bf(vv);
        }
      }
    }
  }
}

// merged Q/K/V projection: blockIdx.z selects which projection; 128x128 tiles.
// z==2 (V) writes the transposed-per-head Vt layout directly (no transpose kernel).
__global__ __launch_bounds__(256) void gemm_qkv_kernel(
    const unsigned short* __restrict__ qb, const unsigned short* __restrict__ kb,
    const unsigned short* __restrict__ vb,
    const unsigned short* __restrict__ wqb, const unsigned short* __restrict__ wkb,
    const unsigned short* __restrict__ wvb,
    const float* __restrict__ bq, const float* __restrict__ bk, const float* __restrict__ bv,
    unsigned short* __restrict__ Qp, unsigned short* __restrict__ Kp,
    unsigned short* __restrict__ Vt) {
  const int z = blockIdx.z;
  if (z == 0) {
    gemm_body<0>(qb, wqb, bq, Qp, 0.125f, blockIdx.x * 128, blockIdx.y * 128);
  } else if (z == 1) {
    gemm_body<0>(kb, wkb, bk, Kp, 1.0f, blockIdx.x * 128, blockIdx.y * 128);
  } else {
    gemm_body<2>(vb, wvb, bv, Vt, 1.0f, blockIdx.x * 128, blockIdx.y * 128);
  }
}

__global__ __launch_bounds__(256) void gemm_o_kernel(
    const unsigned short* __restrict__ A, const unsigned short* __restrict__ Bw,
    const float* __restrict__ bias, float* __restrict__ Cout) {
  gemm_body<1>(A, Bw, bias, Cout, 1.0f, blockIdx.x * 128, blockIdx.y * 128);
}

// ---------------- fused attention: 8 waves, 128 q-rows per block ----------------
// Same r10-proven schedule; K/V staged once per 128 rows (half the staging per row);
// 512 threads; LDS 77824 B (2 blocks/CU = 16 waves/CU):
// [Pw 8x4096 (Qs 18432 overlaps) | K0 9216 | K1 9216 | V0 9216 | V1 9216 | mask 8192]
__device__ __forceinline__ int pf_idx(int row, int col) {
  return row * 64 + (((col >> 2) ^ (row & 7)) << 2) + (col & 3);
}

__global__ __launch_bounds__(512) void attn_kernel(
    const unsigned short* __restrict__ Qp,  // [4096][1024] bf16 (pre-scaled)
    const unsigned short* __restrict__ Kp,  // [4096][1024] bf16
    const unsigned short* __restrict__ Vt,  // [2048][2048] bf16, row=(b*16+h)*64+d, col=key
    const int* __restrict__ mask,           // [2][2048]
    float* __restrict__ attn_out,           // [32][2048][2048] fp32
    unsigned short* __restrict__ Obuf)      // [4096][1024] bf16
{
  __shared__ char smem[77824];
  short* Qs = (short*)smem;                 // 18432 B, init only (overlaps Pw)
  float* maskadd = (float*)(smem + 69632);  // 8192 B

  const int tid = threadIdx.x;
  const int l = tid & 63, w = tid >> 6;  // w in 0..7
  const int lq = l >> 4, lr = l & 15;
  float* Pw = (float*)(smem + w * 4096);  // wave-private 16x64 fp32 tile

  const int tb = blockIdx.x, h = blockIdx.y, bz = blockIdx.z;
  const size_t qrow0 = (size_t)bz * 2048 + tb * 128;
  const size_t krow0 = (size_t)bz * 2048;
  const size_t vrow0 = (size_t)(bz * 16 + h) * 64;

  for (int j = tid; j < 2048; j += 512) {
    int mv = mask[bz * 2048 + j];
    maskadd[j] = (mv == 0) ? -9.0e15f : (float)mv;
  }
  // stage Q block [128][64] -> Qs (stride 72): 1024 uint4, 2 per thread
#pragma unroll
  for (int i = 0; i < 2; ++i) {
    int c = i * 512 + tid, r = c >> 3, c8 = c & 7;
    uint4 v = *(const uint4*)(Qp + (qrow0 + r) * 1024 + h * 64 + c8 * 8);
    *(uint4*)((char*)Qs + r * 144 + c8 * 16) = v;
  }
  __syncthreads();
  bf16x8 aq[2];
#pragma unroll
  for (int kk = 0; kk < 2; ++kk)
    aq[kk] = *(const bf16x8*)((const char*)Qs + (w * 16 + lr) * 144 + kk * 64 + lq * 16);
  __syncthreads();  // Qs dead; Pw regions usable

  // staging geometry: 512 threads cover a 64x64 bf16 tile with 1 uint4 each
  const int r0 = tid >> 3, c8s = tid & 7;

#define KLOAD(d, kcv) \
  { d = *(const uint4*)(Kp + (krow0 + (kcv)*64 + r0) * 1024 + h * 64 + c8s * 8); }
#define VLOAD(d, kcv) \
  { d = *(const uint4*)(Vt + (vrow0 + r0) * 2048 + (kcv)*64 + c8s * 8); }
#define KWRITE(s, buf) \
  { *(uint4*)(smem + 32768 + (buf)*9216 + r0 * 144 + c8s * 16) = s; }
#define VWRITE(s, buf) \
  { *(uint4*)(smem + 51200 + (buf)*9216 + r0 * 144 + c8s * 16) = s; }
#define KFRAG(jt, kk) \
  (*(const bf16x8*)(smem + 32768 + (kc & 1) * 9216 + ((jt)*16 + lr) * 144 + (kk)*64 + lq * 16))
#define VFRAG(dt, kk) \
  (*(const bf16x8*)(smem + 51200 + (kc & 1) * 9216 + ((dt)*16 + lr) * 144 + (kk)*64 + lq * 16))

  // ---------- pass A: denominators (1 barrier per chunk) ----------
  float lacc[4] = {0.f, 0.f, 0.f, 0.f};
  {
    uint4 kr;
    KLOAD(kr, 0);
    KWRITE(kr, 0);
    __syncthreads();
    for (int kc = 0; kc < 32; ++kc) {
      uint4 kn;
      if (kc < 31) KLOAD(kn, kc + 1);
#pragma unroll
      for (int jt = 0; jt < 4; ++jt) {
        f32x4 sa = {0.f, 0.f, 0.f, 0.f};
        sa = MFMA16(aq[0], KFRAG(jt, 0), sa);
        sa = MFMA16(aq[1], KFRAG(jt, 1), sa);
        float ma = maskadd[kc * 64 + jt * 16 + lr];
#pragma unroll
        for (int r = 0; r < 4; ++r) {
          float s_ = fminf(fmaxf(sa[r], -50000.f), 50000.f) + ma;
          lacc[r] += __expf(s_);
        }
      }
      if (kc < 31) KWRITE(kn, (kc + 1) & 1);
      __syncthreads();
    }
  }
#pragma unroll
  for (int r = 0; r < 4; ++r) {
    float t = lacc[r];
    t += __shfl_xor(t, 1, 64);
    t += __shfl_xor(t, 2, 64);
    t += __shfl_xor(t, 4, 64);
    t += __shfl_xor(t, 8, 64);
    lacc[r] = 1.0f / t;  // reciprocal denominator for row lq*4+r
  }

  // ---------- pass B: normalized P stores + PV (1 barrier per chunk) ----------
  const f32x4 fz = {0.f, 0.f, 0.f, 0.f};
  f32x4 oacc[4];
#pragma unroll
  for (int dt = 0; dt < 4; ++dt) oacc[dt] = fz;
  const size_t arow = (size_t)(bz * 16 + h) * 2048 + tb * 128 + w * 16;

  {
    uint4 kr, vr;
    KLOAD(kr, 0);
    VLOAD(vr, 0);
    KWRITE(kr, 0);
    VWRITE(vr, 0);
    __syncthreads();
    for (int kc = 0; kc < 32; ++kc) {
      uint4 kn, vn;
      if (kc < 31) {
        KLOAD(kn, kc + 1);
        VLOAD(vn, kc + 1);
      }
#pragma unroll
      for (int jt = 0; jt < 4; ++jt) {
        f32x4 sa = {0.f, 0.f, 0.f, 0.f};
        sa = MFMA16(aq[0], KFRAG(jt, 0), sa);
        sa = MFMA16(aq[1], KFRAG(jt, 1), sa);
        float ma = maskadd[kc * 64 + jt * 16 + lr];
#pragma unroll
        for (int r = 0; r < 4; ++r) {
          float s_ = fminf(fmaxf(sa[r], -50000.f), 50000.f) + ma;
          Pw[pf_idx(lq * 4 + r, jt * 16 + lr)] = __expf(s_) * lacc[r];
        }
      }
#pragma unroll
      for (int it = 0; it < 4; ++it) {
        int row = it * 4 + lq;
        f32x4 pv4 = *(const f32x4*)&Pw[pf_idx(row, lr * 4)];
        f32x4* dst = (f32x4*)&attn_out[(arow + row) * 2048 + kc * 64 + lr * 4];
        __builtin_nontemporal_store(pv4, dst);
      }
#pragma unroll
      for (int kk = 0; kk < 2; ++kk) {
        f32x4 a0 = *(const f32x4*)&Pw[pf_idx(lr, kk * 32 + lq * 8)];
        f32x4 a1 = *(const f32x4*)&Pw[pf_idx(lr, kk * 32 + lq * 8 + 4)];
        bf16x8 ap;
#pragma unroll
        for (int j = 0; j < 4; ++j) {
          ap[j] = (__bf16)a0[j];
          ap[4 + j] = (__bf16)a1[j];
        }
#pragma unroll
        for (int dt = 0; dt < 4; ++dt)
          oacc[dt] = MFMA16(ap, VFRAG(dt, kk), oacc[dt]);
      }
      if (kc < 31) {
        KWRITE(kn, (kc + 1) & 1);
        VWRITE(vn, (kc + 1) & 1);
      }
      __syncthreads();
    }
  }
#pragma unroll
  for (int dt = 0; dt < 4; ++dt) {
    int col = h * 64 + dt * 16 + lr;
#pragma unroll
    for (int r = 0; r < 4; ++r) {
      int trow = tb * 128 + w * 16 + lq * 4 + r;
      Obuf[((size_t)bz * 2048 + trow) * 1024 + col] = f2bf(oacc[dt][r]);
    }
  }
#undef KLOAD
#undef VLOAD
#undef KWRITE
#undef VWRITE
#undef KFRAG
#undef VFRAG
}

extern "C" void kernel_launch(void* const* d_in, const int* in_sizes, int n_in,
                              void* d_out, int out_size, void* d_ws, size_t ws_size,
                              hipStream_t stream) {
  (void)in_sizes; (void)n_in; (void)out_size; (void)ws_size;
  const float* q  = (const float*)d_in[0];
  const float* k  = (const float*)d_in[1];
  const float* v  = (const float*)d_in[2];
  const int* msk  = (const int*)d_in[3];
  const float* Wq = (const float*)d_in[4];
  const float* bq = (const float*)d_in[5];
  const float* Wk = (const float*)d_in[6];
  const float* bk = (const float*)d_in[7];
  const float* Wv = (const float*)d_in[8];
  const float* bv = (const float*)d_in[9];
  const float* Wo = (const float*)d_in[10];
  const float* bo = (const float*)d_in[11];

  // workspace layout (bf16 elements)
  unsigned short* p = (unsigned short*)d_ws;
  unsigned short* qb  = p; p += 4194304;
  unsigned short* kb  = p; p += 4194304;
  unsigned short* vb  = p; p += 4194304;
  unsigned short* wqb = p; p += 1048576;
  unsigned short* wkb = p; p += 1048576;
  unsigned short* wvb = p; p += 1048576;
  unsigned short* wob = p; p += 1048576;
  unsigned short* Qp  = p; p += 4194304;
  unsigned short* Kp  = p; p += 4194304;
  unsigned short* Vtg = p; p += 4194304;
  unsigned short* Ob  = p; p += 4194304;

  cvt_all_kernel<<<16384, 256, 0, stream>>>(q, k, v, Wq, Wk, Wv, Wo,
                                            qb, kb, vb, wqb, wkb, wvb, wob);

  gemm_qkv_kernel<<<dim3(32, 8, 3), 256, 0, stream>>>(qb, kb, vb, wqb, wkb, wvb,
                                                      bq, bk, bv, Qp, Kp, Vtg);

  float* outp = (float*)d_out;
  float* attnp = outp + 4194304;
  attn_kernel<<<dim3(16, 16, 2), 512, 0, stream>>>(Qp, Kp, Vtg, msk, attnp, Ob);

  gemm_o_kernel<<<dim3(32, 8), 256, 0, stream>>>(Ob, wob, bo, outp);
}

// Round 16
// 329.031 us; speedup vs baseline: 1.0480x; 1.0480x over previous
//
#include <hip/hip_runtime.h>
#include <hip/hip_bf16.h>

// MultiHeadAttention fused pipeline for MI355X (gfx950).
// b=2, t=s=2048, E=1024, H=16, D=64. Outputs: out fp32 [2,2048,1024], attn fp32 [32,2048,2048].

typedef __attribute__((ext_vector_type(8))) __bf16 bf16x8;
typedef __attribute__((ext_vector_type(4))) float f32x4;
typedef __attribute__((ext_vector_type(8))) unsigned short us8;

#define MFMA16(A, B, C) __builtin_amdgcn_mfma_f32_16x16x32_bf16(A, B, C, 0, 0, 0)

__device__ __forceinline__ unsigned short f2bf(float f) {
  __bf16 h = (__bf16)f;
  return __builtin_bit_cast(unsigned short, h);
}

// ---------------- fused fp32 -> bf16 convert for all 7 tensors ----------------
__global__ __launch_bounds__(256) void cvt_all_kernel(
    const float* __restrict__ q, const float* __restrict__ k, const float* __restrict__ v,
    const float* __restrict__ Wq, const float* __restrict__ Wk,
    const float* __restrict__ Wv, const float* __restrict__ Wo,
    unsigned short* __restrict__ qb, unsigned short* __restrict__ kb,
    unsigned short* __restrict__ vb, unsigned short* __restrict__ wqb,
    unsigned short* __restrict__ wkb, unsigned short* __restrict__ wvb,
    unsigned short* __restrict__ wob) {
  const int bid = blockIdx.x;
  const float* src;
  unsigned short* dst;
  int i;
  if (bid < 4096)       { src = q; dst = qb; i = bid * 256 + threadIdx.x; }
  else if (bid < 8192)  { src = k; dst = kb; i = (bid - 4096) * 256 + threadIdx.x; }
  else if (bid < 12288) { src = v; dst = vb; i = (bid - 8192) * 256 + threadIdx.x; }
  else {
    int wsel = (bid - 12288) >> 10;
    i = ((bid - 12288) & 1023) * 256 + threadIdx.x;
    src = wsel == 0 ? Wq : wsel == 1 ? Wk : wsel == 2 ? Wv : Wo;
    dst = wsel == 0 ? wqb : wsel == 1 ? wkb : wsel == 2 ? wvb : wob;
  }
  float4 vv = ((const float4*)src)[i];
  ushort4 o;
  o.x = f2bf(vv.x); o.y = f2bf(vv.y); o.z = f2bf(vv.z); o.w = f2bf(vv.w);
  ((ushort4*)dst)[i] = o;
}

// ------- GEMM body (r10-proven): C[128x128 tile] = A @ W^T + bias, *scale -------
// MODE: 0 = bf16 [M][1024], 1 = fp32 [M][1024], 2 = bf16 transposed-per-head Vt layout
template <int MODE>
__device__ __forceinline__ void gemm_body(
    const unsigned short* __restrict__ A, const unsigned short* __restrict__ Bw,
    const float* __restrict__ bias, void* __restrict__ Cout, float scale,
    int m0, int n0) {
  __shared__ short As[128 * 72];
  __shared__ short Bs[128 * 72];
  const int tid = threadIdx.x;
  const int l = tid & 63, w = tid >> 6;
  const int lq = l >> 4, lr = l & 15;
  const int wr = w >> 1, wc = w & 1;

  uint4 va[4], vb[4];
#pragma unroll
  for (int i = 0; i < 4; ++i) {
    int c = i * 256 + tid, r = c >> 3, c8 = c & 7;
    va[i] = *(const uint4*)(A + (size_t)(m0 + r) * 1024 + c8 * 8);
    vb[i] = *(const uint4*)(Bw + (size_t)(n0 + r) * 1024 + c8 * 8);
  }
  const f32x4 fz = {0.f, 0.f, 0.f, 0.f};
  f32x4 acc[4][4];
#pragma unroll
  for (int m = 0; m < 4; ++m)
#pragma unroll
    for (int n = 0; n < 4; ++n) acc[m][n] = fz;

  for (int ks = 0; ks < 16; ++ks) {
    __syncthreads();
#pragma unroll
    for (int i = 0; i < 4; ++i) {
      int c = i * 256 + tid, r = c >> 3, c8 = c & 7;
      *(uint4*)((char*)As + r * 144 + c8 * 16) = va[i];
      *(uint4*)((char*)Bs + r * 144 + c8 * 16) = vb[i];
    }
    __syncthreads();
    if (ks < 15) {
      int k0 = (ks + 1) * 64;
#pragma unroll
      for (int i = 0; i < 4; ++i) {
        int c = i * 256 + tid, r = c >> 3, c8 = c & 7;
        va[i] = *(const uint4*)(A + (size_t)(m0 + r) * 1024 + k0 + c8 * 8);
        vb[i] = *(const uint4*)(Bw + (size_t)(n0 + r) * 1024 + k0 + c8 * 8);
      }
    }
#pragma unroll
    for (int kk = 0; kk < 2; ++kk) {
      bf16x8 af[4], bfr[4];
#pragma unroll
      for (int m = 0; m < 4; ++m)
        af[m] = *(const bf16x8*)((const char*)As + (wr * 64 + m * 16 + lr) * 144 + kk * 64 + lq * 16);
#pragma unroll
      for (int n = 0; n < 4; ++n)
        bfr[n] = *(const bf16x8*)((const char*)Bs + (wc * 64 + n * 16 + lr) * 144 + kk * 64 + lq * 16);
#pragma unroll
      for (int m = 0; m < 4; ++m)
#pragma unroll
        for (int n = 0; n < 4; ++n) acc[m][n] = MFMA16(af[m], bfr[n], acc[m][n]);
    }
  }
  // epilogue: C row = (lane>>4)*4+reg, col = lane&15
#pragma unroll
  for (int n = 0; n < 4; ++n) {
    const int col = n0 + wc * 64 + n * 16 + lr;
    const float bv_ = bias[col];
#pragma unroll
    for (int m = 0; m < 4; ++m) {
      const int rowb = m0 + wr * 64 + m * 16 + lq * 4;
      if (MODE == 2) {
        // direct transposed-per-head write: Vt[((b*16+h)*64+d)][key], 4 consecutive keys
        const int b_ = rowb >> 11, s = rowb & 2047;
        const size_t vtrow = (size_t)(b_ * 16 + (col >> 6)) * 64 + (col & 63);
        ushort4 o;
        o.x = f2bf(acc[m][n][0] + bv_);
        o.y = f2bf(acc[m][n][1] + bv_);
        o.z = f2bf(acc[m][n][2] + bv_);
        o.w = f2bf(acc[m][n][3] + bv_);
        *(ushort4*)((unsigned short*)Cout + vtrow * 2048 + s) = o;
      } else {
#pragma unroll
        for (int r = 0; r < 4; ++r) {
          float vv = (acc[m][n][r] + bv_) * scale;
          if (MODE == 1)
            ((float*)Cout)[(size_t)(rowb + r) * 1024 + col] = vv;
          else
            ((unsigned short*)Cout)[(size_t)(rowb + r) * 1024 + col] = f2bf(vv);
        }
      }
    }
  }
}

// merged Q/K/V projection: blockIdx.z selects which projection; 128x128 tiles.
// z==2 (V) writes the transposed-per-head Vt layout directly (no transpose kernel).
__global__ __launch_bounds__(256) void gemm_qkv_kernel(
    const unsigned short* __restrict__ qb, const unsigned short* __restrict__ kb,
    const unsigned short* __restrict__ vb,
    const unsigned short* __restrict__ wqb, const unsigned short* __restrict__ wkb,
    const unsigned short* __restrict__ wvb,
    const float* __restrict__ bq, const float* __restrict__ bk, const float* __restrict__ bv,
    unsigned short* __restrict__ Qp, unsigned short* __restrict__ Kp,
    unsigned short* __restrict__ Vt) {
  const int z = blockIdx.z;
  if (z == 0) {
    gemm_body<0>(qb, wqb, bq, Qp, 0.125f, blockIdx.x * 128, blockIdx.y * 128);
  } else if (z == 1) {
    gemm_body<0>(kb, wkb, bk, Kp, 1.0f, blockIdx.x * 128, blockIdx.y * 128);
  } else {
    gemm_body<2>(vb, wvb, bv, Vt, 1.0f, blockIdx.x * 128, blockIdx.y * 128);
  }
}

__global__ __launch_bounds__(256) void gemm_o_kernel(
    const unsigned short* __restrict__ A, const unsigned short* __restrict__ Bw,
    const float* __restrict__ bias, float* __restrict__ Cout) {
  gemm_body<1>(A, Bw, bias, Cout, 1.0f, blockIdx.x * 128, blockIdx.y * 128);
}

// ---------------- fused attention (r14-proven) + XCD-aware block swizzle ----------------
// LDS 61440 B (2 blocks/CU): [Pw 4x4096 (Qs overlaps) | K0 | K1 | V0 | V1 | mask 8192]
// Swizzle: flat = bx + 32*by (0..511); swz = (flat&7)*64 + flat>>3 (bijective transpose)
// -> each XCD (round-robin over dispatch order) works on 2 heads' K/V = 2 MB, L2-resident.
__device__ __forceinline__ int pf_idx(int row, int col) {
  return row * 64 + (((col >> 2) ^ (row & 7)) << 2) + (col & 3);
}

__global__ __launch_bounds__(256) void attn_kernel(
    const unsigned short* __restrict__ Qp,  // [4096][1024] bf16 (pre-scaled)
    const unsigned short* __restrict__ Kp,  // [4096][1024] bf16
    const unsigned short* __restrict__ Vt,  // [2048][2048] bf16, row=(b*16+h)*64+d, col=key
    const int* __restrict__ mask,           // [2][2048]
    float* __restrict__ attn_out,           // [32][2048][2048] fp32
    unsigned short* __restrict__ Obuf)      // [4096][1024] bf16
{
  __shared__ char smem[61440];
  short* Qs = (short*)smem;                 // 9216 B, init only (overlaps Pw)
  float* maskadd = (float*)(smem + 53248);  // 8192 B

  const int tid = threadIdx.x;
  const int l = tid & 63, w = tid >> 6;
  const int lq = l >> 4, lr = l & 15;
  float* Pw = (float*)(smem + w * 4096);  // wave-private 16x64 fp32 tile

  // XCD-aware bijective swizzle of (tb, h)
  const int flat = blockIdx.x + (blockIdx.y << 5);   // 0..511
  const int swz = (flat & 7) * 64 + (flat >> 3);     // transpose 8x64, bijective
  const int tb = swz & 31, h = swz >> 5;
  const int bz = blockIdx.z;

  const size_t qrow0 = (size_t)bz * 2048 + tb * 64;
  const size_t krow0 = (size_t)bz * 2048;
  const size_t vrow0 = (size_t)(bz * 16 + h) * 64;

  for (int j = tid; j < 2048; j += 256) {
    int mv = mask[bz * 2048 + j];
    maskadd[j] = (mv == 0) ? -9.0e15f : (float)mv;
  }
#pragma unroll
  for (int i = 0; i < 2; ++i) {
    int c = i * 256 + tid, r = c >> 3, c8 = c & 7;
    uint4 v = *(const uint4*)(Qp + (qrow0 + r) * 1024 + h * 64 + c8 * 8);
    *(uint4*)((char*)Qs + r * 144 + c8 * 16) = v;
  }
  __syncthreads();
  bf16x8 aq[2];
#pragma unroll
  for (int kk = 0; kk < 2; ++kk)
    aq[kk] = *(const bf16x8*)((const char*)Qs + (w * 16 + lr) * 144 + kk * 64 + lq * 16);
  __syncthreads();  // Qs dead; Pw regions usable

  const int r0 = tid >> 3, c8s = tid & 7;

#define KLOAD(d, kcv)                                                                       \
  {                                                                                         \
    d[0] = *(const uint4*)(Kp + (krow0 + (kcv)*64 + r0) * 1024 + h * 64 + c8s * 8);         \
    d[1] = *(const uint4*)(Kp + (krow0 + (kcv)*64 + 32 + r0) * 1024 + h * 64 + c8s * 8);    \
  }
#define VLOAD(d, kcv)                                                                       \
  {                                                                                         \
    d[0] = *(const uint4*)(Vt + (vrow0 + r0) * 2048 + (kcv)*64 + c8s * 8);                  \
    d[1] = *(const uint4*)(Vt + (vrow0 + 32 + r0) * 2048 + (kcv)*64 + c8s * 8);             \
  }
#define KWRITE(s, buf)                                                          \
  {                                                                             \
    *(uint4*)(smem + 16384 + (buf)*9216 + r0 * 144 + c8s * 16) = s[0];          \
    *(uint4*)(smem + 16384 + (buf)*9216 + (32 + r0) * 144 + c8s * 16) = s[1];   \
  }
#define VWRITE(s, buf)                                                          \
  {                                                                             \
    *(uint4*)(smem + 34816 + (buf)*9216 + r0 * 144 + c8s * 16) = s[0];          \
    *(uint4*)(smem + 34816 + (buf)*9216 + (32 + r0) * 144 + c8s * 16) = s[1];   \
  }
#define KFRAG(jt, kk) \
  (*(const bf16x8*)(smem + 16384 + (kc & 1) * 9216 + ((jt)*16 + lr) * 144 + (kk)*64 + lq * 16))
#define VFRAG(dt, kk) \
  (*(const bf16x8*)(smem + 34816 + (kc & 1) * 9216 + ((dt)*16 + lr) * 144 + (kk)*64 + lq * 16))

  // ---------- pass A: denominators (1 barrier per chunk) ----------
  float lacc[4] = {0.f, 0.f, 0.f, 0.f};
  {
    uint4 kr[2];
    KLOAD(kr, 0);
    KWRITE(kr, 0);
    __syncthreads();
    for (int kc = 0; kc < 32; ++kc) {
      uint4 kn[2];
      if (kc < 31) KLOAD(kn, kc + 1);
#pragma unroll
      for (int jt = 0; jt < 4; ++jt) {
        f32x4 sa = {0.f, 0.f, 0.f, 0.f};
        sa = MFMA16(aq[0], KFRAG(jt, 0), sa);
        sa = MFMA16(aq[1], KFRAG(jt, 1), sa);
        float ma = maskadd[kc * 64 + jt * 16 + lr];
#pragma unroll
        for (int r = 0; r < 4; ++r) {
          float s_ = fminf(fmaxf(sa[r], -50000.f), 50000.f) + ma;
          lacc[r] += __expf(s_);
        }
      }
      if (kc < 31) KWRITE(kn, (kc + 1) & 1);
      __syncthreads();
    }
  }
#pragma unroll
  for (int r = 0; r < 4; ++r) {
    float t = lacc[r];
    t += __shfl_xor(t, 1, 64);
    t += __shfl_xor(t, 2, 64);
    t += __shfl_xor(t, 4, 64);
    t += __shfl_xor(t, 8, 64);
    lacc[r] = 1.0f / t;  // reciprocal denominator for row lq*4+r
  }

  // ---------- pass B: normalized P stores + PV (1 barrier per chunk) ----------
  const f32x4 fz = {0.f, 0.f, 0.f, 0.f};
  f32x4 oacc[4];
#pragma unroll
  for (int dt = 0; dt < 4; ++dt) oacc[dt] = fz;
  const size_t arow = (size_t)(bz * 16 + h) * 2048 + tb * 64 + w * 16;

  {
    uint4 kr[2], vr[2];
    KLOAD(kr, 0);
    VLOAD(vr, 0);
    KWRITE(kr, 0);
    VWRITE(vr, 0);
    __syncthreads();
    for (int kc = 0; kc < 32; ++kc) {
      uint4 kn[2], vn[2];
      if (kc < 31) {
        KLOAD(kn, kc + 1);
        VLOAD(vn, kc + 1);
      }
#pragma unroll
      for (int jt = 0; jt < 4; ++jt) {
        f32x4 sa = {0.f, 0.f, 0.f, 0.f};
        sa = MFMA16(aq[0], KFRAG(jt, 0), sa);
        sa = MFMA16(aq[1], KFRAG(jt, 1), sa);
        float ma = maskadd[kc * 64 + jt * 16 + lr];
#pragma unroll
        for (int r = 0; r < 4; ++r) {
          float s_ = fminf(fmaxf(sa[r], -50000.f), 50000.f) + ma;
          Pw[pf_idx(lq * 4 + r, jt * 16 + lr)] = __expf(s_) * lacc[r];
        }
      }
#pragma unroll
      for (int it = 0; it < 4; ++it) {
        int row = it * 4 + lq;
        f32x4 pv4 = *(const f32x4*)&Pw[pf_idx(row, lr * 4)];
        f32x4* dst = (f32x4*)&attn_out[(arow + row) * 2048 + kc * 64 + lr * 4];
        __builtin_nontemporal_store(pv4, dst);
      }
#pragma unroll
      for (int kk = 0; kk < 2; ++kk) {
        f32x4 a0 = *(const f32x4*)&Pw[pf_idx(lr, kk * 32 + lq * 8)];
        f32x4 a1 = *(const f32x4*)&Pw[pf_idx(lr, kk * 32 + lq * 8 + 4)];
        bf16x8 ap;
#pragma unroll
        for (int j = 0; j < 4; ++j) {
          ap[j] = (__bf16)a0[j];
          ap[4 + j] = (__bf16)a1[j];
        }
#pragma unroll
        for (int dt = 0; dt < 4; ++dt)
          oacc[dt] = MFMA16(ap, VFRAG(dt, kk), oacc[dt]);
      }
      if (kc < 31) {
        KWRITE(kn, (kc + 1) & 1);
        VWRITE(vn, (kc + 1) & 1);
      }
      __syncthreads();
    }
  }
#pragma unroll
  for (int dt = 0; dt < 4; ++dt) {
    int col = h * 64 + dt * 16 + lr;
#pragma unroll
    for (int r = 0; r < 4; ++r) {
      int trow = tb * 64 + w * 16 + lq * 4 + r;
      Obuf[((size_t)bz * 2048 + trow) * 1024 + col] = f2bf(oacc[dt][r]);
    }
  }
#undef KLOAD
#undef VLOAD
#undef KWRITE
#undef VWRITE
#undef KFRAG
#undef VFRAG
}

extern "C" void kernel_launch(void* const* d_in, const int* in_sizes, int n_in,
                              void* d_out, int out_size, void* d_ws, size_t ws_size,
                              hipStream_t stream) {
  (void)in_sizes; (void)n_in; (void)out_size; (void)ws_size;
  const float* q  = (const float*)d_in[0];
  const float* k  = (const float*)d_in[1];
  const float* v  = (const float*)d_in[2];
  const int* msk  = (const int*)d_in[3];
  const float* Wq = (const float*)d_in[4];
  const float* bq = (const float*)d_in[5];
  const float* Wk = (const float*)d_in[6];
  const float* bk = (const float*)d_in[7];
  const float* Wv = (const float*)d_in[8];
  const float* bv = (const float*)d_in[9];
  const float* Wo = (const float*)d_in[10];
  const float* bo = (const float*)d_in[11];

  // workspace layout (bf16 elements)
  unsigned short* p = (unsigned short*)d_ws;
  unsigned short* qb  = p; p += 4194304;
  unsigned short* kb  = p; p += 4194304;
  unsigned short* vb  = p; p += 4194304;
  unsigned short* wqb = p; p += 1048576;
  unsigned short* wkb = p; p += 1048576;
  unsigned short* wvb = p; p += 1048576;
  unsigned short* wob = p; p += 1048576;
  unsigned short* Qp  = p; p += 4194304;
  unsigned short* Kp  = p; p += 4194304;
  unsigned short* Vtg = p; p += 4194304;
  unsigned short* Ob  = p; p += 4194304;

  cvt_all_kernel<<<16384, 256, 0, stream>>>(q, k, v, Wq, Wk, Wv, Wo,
                                            qb, kb, vb, wqb, wkb, wvb, wob);

  gemm_qkv_kernel<<<dim3(32, 8, 3), 256, 0, stream>>>(qb, kb, vb, wqb, wkb, wvb,
                                                      bq, bk, bv, Qp, Kp, Vtg);

  float* outp = (float*)d_out;
  float* attnp = outp + 4194304;
  attn_kernel<<<dim3(32, 16, 2), 256, 0, stream>>>(Qp, Kp, Vtg, msk, attnp, Ob);

  gemm_o_kernel<<<dim3(32, 8), 256, 0, stream>>>(Ob, wob, bo, outp);
}